// Round 2
// baseline (237.673 us; speedup 1.0000x reference)
//
#include <hip/hip_runtime.h>
#include <hip/hip_bf16.h>

// PyramidLevel1Block: gather(cur_x by up_idx) ++ pre_x -> GEMM(192x128) -> BN -> ReLU
// B=4, M=65536, N=16384, C_pre=64, C_cur=128, C_in=192, D=128.
//
// Kernel 1: transpose+convert cur_x (B,128,N) fp32 -> curT (B,N,128) bf16 (d_ws)
//           so the per-row gather is 256 B contiguous instead of 128 x 64KB-strided lines.
// Kernel 2: 64 rows/block, stage x-tile [64][192] bf16 in LDS (stride 200 = 400 B,
//           16B-aligned frags, banks spread), W-frags in registers per wave
//           (wave w owns cols [32w,32w+32)), 16x16x32 bf16 MFMA, fused BN+ReLU epilogue.

typedef short bhalf8 __attribute__((ext_vector_type(8)));
typedef float f32x4 __attribute__((ext_vector_type(4)));
typedef unsigned int u32x4 __attribute__((ext_vector_type(4)));

__device__ __forceinline__ short f2bf(float f) {
  // round-to-nearest-even float -> bf16 (finite inputs only)
  unsigned int u = __float_as_uint(f);
  unsigned int r = (u + 0x7fffu + ((u >> 16) & 1u)) >> 16;
  return (short)r;
}

// ---------------- Kernel 1: cur_x (B,128,16384) f32 -> curT (B,16384,128) bf16 ---
__global__ __launch_bounds__(256) void transpose_cur(const float* __restrict__ cur,
                                                     short* __restrict__ curT) {
  __shared__ float tile[128][65];  // +1 pad: conflict-free col reads
  const int b = blockIdx.y;
  const int n0 = blockIdx.x << 6;  // 64 n per block
  const float* src = cur + (size_t)b * 128 * 16384;
  // load 128 c x 64 n, float4-vectorized, coalesced along n (streamed once)
#pragma unroll
  for (int it = 0; it < 8; ++it) {
    int v = it * 256 + threadIdx.x;
    int cc = v >> 4;
    int nq = (v & 15) << 2;
    f32x4 f = __builtin_nontemporal_load(
        reinterpret_cast<const f32x4*>(&src[(size_t)cc * 16384 + n0 + nq]));
    tile[cc][nq + 0] = f[0];
    tile[cc][nq + 1] = f[1];
    tile[cc][nq + 2] = f[2];
    tile[cc][nq + 3] = f[3];
  }
  __syncthreads();
  short* dst = curT + ((size_t)b * 16384 + n0) * 128;
  // store 64 n rows x 128 c, 16B per lane, coalesced along c
#pragma unroll
  for (int it = 0; it < 4; ++it) {
    int v = it * 256 + threadIdx.x;
    int nn = v >> 4;
    int c8 = (v & 15) << 3;
    bhalf8 pk;
#pragma unroll
    for (int j = 0; j < 8; ++j) pk[j] = f2bf(tile[c8 + j][nn]);
    *reinterpret_cast<bhalf8*>(&dst[(size_t)nn * 128 + c8]) = pk;
  }
}

// ---------------- Kernel 2: fused gather+GEMM+BN+ReLU -----------------------------
#define NBLK 2048  // row-groups = 4096 (64 rows each), 2 per block

__global__ __launch_bounds__(256, 3) void fused_gemm(
    const float* __restrict__ pre_x,  // (4, 64, 65536)
    const int* __restrict__ up_idx,   // (4, 65536)
    const float* __restrict__ w,      // (192, 128)
    const float* __restrict__ bias,   // (128)
    const float* __restrict__ gamma, const float* __restrict__ beta,
    const float* __restrict__ rmean, const float* __restrict__ rvar,
    const short* __restrict__ curT,  // (4, 16384, 128) bf16
    float* __restrict__ out)         // (4, 65536, 128) f32
{
  // x-tile: 64 rows x 192 k (bf16), row stride 200 (400 B: 16B-aligned, bank-spread)
  __shared__ short x_lds[64 * 200];
  const int tid = threadIdx.x;
  const int lane = tid & 63;
  const int wv = tid >> 6;    // wave 0..3 -> cols [32wv, 32wv+32)
  const int c = lane & 15;    // MFMA: A-row / C-col / B-col index
  const int g = lane >> 4;    // MFMA quad: k-offset group (A/B), row group (C)

  // W fragments in registers: bf[s][ct][j] = w[32s + 8g + j][32wv + 16ct + c]
  bhalf8 bf[6][2];
#pragma unroll
  for (int s = 0; s < 6; ++s)
#pragma unroll
    for (int ct = 0; ct < 2; ++ct) {
      const int col = 32 * wv + 16 * ct + c;
#pragma unroll
      for (int j = 0; j < 8; ++j)
        bf[s][ct][j] = f2bf(w[(32 * s + 8 * g + j) * 128 + col]);
    }

  // fold bias + BN into y = dot*scale + shift
  float scale[2], shift[2];
#pragma unroll
  for (int ct = 0; ct < 2; ++ct) {
    const int d = 32 * wv + 16 * ct + c;
    float sc = gamma[d] * rsqrtf(rvar[d] + 1e-5f);
    scale[ct] = sc;
    shift[ct] = (bias[d] - rmean[d]) * sc + beta[d];
  }

  for (int t = 0; t < 2; ++t) {
    const long rg = blockIdx.x + (long)t * NBLK;  // row-group id, 64 rows each
    const long r0 = rg << 6;
    const int b = (int)(r0 >> 16);     // / 65536
    const int m0 = (int)(r0 & 65535);  // % 65536 (64-aligned)
    if (t) __syncthreads();  // LDS reuse fence

    // stage pre_x: 64 c x 64 m, coalesced float4 along m, transposed into LDS
    {
      const float* pb = pre_x + (size_t)b * 64 * 65536 + m0;
#pragma unroll
      for (int it = 0; it < 4; ++it) {
        int v = it * 256 + tid;
        int cc = v >> 4;            // 0..63 channel
        int mq = (v & 15) << 2;     // 0..60 row quad
        f32x4 f = __builtin_nontemporal_load(
            reinterpret_cast<const f32x4*>(&pb[(size_t)cc * 65536 + mq]));
        x_lds[(mq + 0) * 200 + cc] = f2bf(f[0]);
        x_lds[(mq + 1) * 200 + cc] = f2bf(f[1]);
        x_lds[(mq + 2) * 200 + cc] = f2bf(f[2]);
        x_lds[(mq + 3) * 200 + cc] = f2bf(f[3]);
      }
    }
    // stage gathered features: per row, 256 B contiguous from curT[b][idx[r]][:]
    {
#pragma unroll
      for (int it = 0; it < 4; ++it) {
        int mm = it * 16 + (tid >> 4);  // row in tile
        int seg = tid & 15;             // 16 B segment
        int n = up_idx[r0 + mm];
        const short* srcp = curT + ((size_t)b * 16384 + n) * 128 + seg * 8;
        *reinterpret_cast<u32x4*>(&x_lds[mm * 200 + 64 + seg * 8]) =
            *reinterpret_cast<const u32x4*>(srcp);
      }
    }
    __syncthreads();

    // compute: 4 row-tiles x (2 col-tiles of this wave) x 6 k-steps
#pragma unroll
    for (int rt = 0; rt < 4; ++rt) {
      bhalf8 a[6];
#pragma unroll
      for (int s = 0; s < 6; ++s)
        a[s] = *reinterpret_cast<const bhalf8*>(
            &x_lds[(16 * rt + c) * 200 + 32 * s + 8 * g]);
      f32x4 acc0 = {0.f, 0.f, 0.f, 0.f};
      f32x4 acc1 = {0.f, 0.f, 0.f, 0.f};
#pragma unroll
      for (int s = 0; s < 6; ++s) {
        acc0 = __builtin_amdgcn_mfma_f32_16x16x32_bf16(a[s], bf[s][0], acc0, 0, 0, 0);
        acc1 = __builtin_amdgcn_mfma_f32_16x16x32_bf16(a[s], bf[s][1], acc1, 0, 0, 0);
      }
      // epilogue: C[row=4g+i][col=c], fused scale/shift + ReLU, nontemporal stores
      float* ob = out + (size_t)(r0 + 16 * rt + 4 * g) * 128 + 32 * wv;
#pragma unroll
      for (int i = 0; i < 4; ++i) {
        float v0 = fmaxf(acc0[i] * scale[0] + shift[0], 0.f);
        float v1 = fmaxf(acc1[i] * scale[1] + shift[1], 0.f);
        __builtin_nontemporal_store(v0, ob + (size_t)i * 128 + c);
        __builtin_nontemporal_store(v1, ob + (size_t)i * 128 + 16 + c);
      }
    }
  }
}

extern "C" void kernel_launch(void* const* d_in, const int* in_sizes, int n_in,
                              void* d_out, int out_size, void* d_ws, size_t ws_size,
                              hipStream_t stream) {
  const float* pre_x = (const float*)d_in[0];
  const float* cur_x = (const float*)d_in[1];
  const int* up_idx = (const int*)d_in[2];
  const float* w = (const float*)d_in[3];
  const float* bias = (const float*)d_in[4];
  const float* gamma = (const float*)d_in[5];
  const float* beta = (const float*)d_in[6];
  const float* rmean = (const float*)d_in[7];
  const float* rvar = (const float*)d_in[8];
  float* out = (float*)d_out;
  short* curT = (short*)d_ws;  // (4, 16384, 128) bf16 = 16.8 MB

  hipLaunchKernelGGL(transpose_cur, dim3(256, 4), dim3(256), 0, stream, cur_x, curT);
  hipLaunchKernelGGL(fused_gemm, dim3(NBLK), dim3(256), 0, stream, pre_x, up_idx, w,
                     bias, gamma, beta, rmean, rvar, curT, out);
}